// Round 3
// baseline (226.678 us; speedup 1.0000x reference)
//
#include <hip/hip_runtime.h>

#define S   4
#define BB  8
#define CC  64
#define HH  128
#define WW  256
#define KC  8            // channels per LDS chunk
#define TH  8            // rows per block
#define TW  64           // cols per block
#define TROWS 16         // TH + 2S
#define PITCH 72         // TW + 2S
#define NGRP 3           // di groups: {-4..-2}, {-1..1}, {2..4}
#define PX   4           // pixels per thread
#define NTX  16          // TW / PX
#define NT   384         // NTX * TH * NGRP

// Map displacement (di,dj) -> output index in the reference's enumeration order.
__device__ constexpr int ord_idx(int di, int dj) {
  int i = di < 0 ? -di : di;
  int j = dj < 0 ? -dj : dj;
  if (i == 0 && j == 0) return 0;
  if (j == 0) return 1 + (i - 1) * 20 + (di > 0 ? 0 : 1);
  if (i == 0) return 1 + (j - 1) * 20 + (dj > 0 ? 2 : 3);
  return 1 + (i - 1) * 20 + 4 + (j - 1) * 4 +
         (di > 0 ? (dj > 0 ? 0 : 2) : (dj > 0 ? 1 : 3));
}

__global__ __launch_bounds__(NT, 3)   // cap VGPR at ~170, 3 waves/SIMD
void costvol_kernel(const float* __restrict__ src,
                    const float* __restrict__ tgt,
                    float* __restrict__ out) {
  __shared__ __align__(16) float lds[KC][TROWS][PITCH];

  const int tx  = threadIdx.x;            // 0..15
  const int ty  = threadIdx.y;            // 0..7  (row within tile)
  const int tz  = threadIdx.z;            // 0..2  (di group)
  const int tid = tz * (NTX * TH) + ty * NTX + tx;
  const int bx  = blockIdx.x;             // 0..3
  const int by  = blockIdx.y;             // 0..15
  const int b   = blockIdx.z;             // 0..7

  const int w0b = bx * TW;
  const int h0  = by * TH;
  const int h   = h0 + ty;
  const int w0  = w0b + tx * PX;          // 16B-aligned pixel quad
  const int di_base = tz * 3 - S;         // -4, -1, 2 (wave-uniform)

  // 27 displacements per group x 4 pixels -> 108 accumulator VGPRs.
  float acc[27][PX];
#pragma unroll
  for (int o = 0; o < 27; ++o)
#pragma unroll
    for (int k = 0; k < PX; ++k) acc[o][k] = 0.f;

  for (int c0 = 0; c0 < CC; c0 += KC) {
    __syncthreads();   // protect LDS against readers of previous chunk

    // ---- stage tgt chunk into LDS, zero-padded halo, all bounds here ----
    // KC*TROWS*PITCH = 9216 floats = 2304 float4 = exactly 6 per thread.
#pragma unroll
    for (int k = 0; k < 6; ++k) {
      const int f4  = tid + k * NT;           // 0..2303
      const int c   = f4 / 288;               // 288 = TROWS*18
      const int rem = f4 - c * 288;
      const int r   = rem / 18;
      const int cq  = rem - r * 18;
      const int gh  = h0 - S + r;
      const int gw  = w0b - S + cq * 4;
      float4 v = make_float4(0.f, 0.f, 0.f, 0.f);
      if ((unsigned)gh < (unsigned)HH && gw >= 0 && gw + 3 < WW) {
        v = *reinterpret_cast<const float4*>(
              tgt + (((size_t)b * CC + (c0 + c)) * HH + gh) * WW + gw);
      }
      *reinterpret_cast<float4*>(&lds[c][r][cq * 4]) = v;
    }

    __syncthreads();

    // ---- compute: c outer (4 src regs live), di inner ----
#pragma unroll
    for (int c = 0; c < KC; ++c) {
      const float4 s4 = *reinterpret_cast<const float4*>(
          src + (((size_t)b * CC + (c0 + c)) * HH + h) * WW + w0);
      const float sv[PX] = {s4.x, s4.y, s4.z, s4.w};

#pragma unroll
      for (int gi = 0; gi < 3; ++gi) {
        const int di  = di_base + gi;       // runtime, wave-uniform
        const int row = ty + S - di;        // in [0,15]
        // 12-float window: 3 aligned ds_read_b128
        const float4* rp =
            reinterpret_cast<const float4*>(&lds[c][row][tx * PX]);
        float win[12];
#pragma unroll
        for (int q = 0; q < 3; ++q) {
          const float4 t = rp[q];
          win[4 * q]     = t.x;
          win[4 * q + 1] = t.y;
          win[4 * q + 2] = t.z;
          win[4 * q + 3] = t.w;
        }
#pragma unroll
        for (int dj = -S; dj <= S; ++dj) {
          const int o = gi * 9 + (dj + S);  // compile-time accumulator slot
#pragma unroll
          for (int k = 0; k < PX; ++k)
            acc[o][k] += sv[k] * win[k + S - dj];
        }
      }
    }
  }

  // ---- store: 27 coalesced float4 stores per thread ----
  const size_t HW = (size_t)HH * WW;
  float* op = out + (size_t)b * 81 * HW + (size_t)h * WW + w0;
#pragma unroll
  for (int gi = 0; gi < 3; ++gi) {
    const int di = di_base + gi;            // wave-uniform scalar
#pragma unroll
    for (int dj = -S; dj <= S; ++dj) {
      const int o    = ord_idx(di, dj);     // cheap scalar epilogue
      const int slot = gi * 9 + (dj + S);
      *reinterpret_cast<float4*>(op + (size_t)o * HW) =
          make_float4(acc[slot][0], acc[slot][1], acc[slot][2], acc[slot][3]);
    }
  }
}

extern "C" void kernel_launch(void* const* d_in, const int* in_sizes, int n_in,
                              void* d_out, int out_size, void* d_ws, size_t ws_size,
                              hipStream_t stream) {
  const float* src = (const float*)d_in[0];
  const float* tgt = (const float*)d_in[1];
  float* out = (float*)d_out;
  // search_range (d_in[2]) is fixed at 4 per setup_inputs; geometry hardcoded.
  dim3 grid(WW / TW, HH / TH, BB);   // (4, 16, 8)
  dim3 block(NTX, TH, NGRP);         // 384 threads
  costvol_kernel<<<grid, block, 0, stream>>>(src, tgt, out);
}

// Round 4
// 149.794 us; speedup vs baseline: 1.5133x; 1.5133x over previous
//
#include <hip/hip_runtime.h>

#define S    4
#define BB   8
#define CC   64
#define HH   128
#define WW   256
#define KC   4            // channels per LDS chunk
#define TH   8            // rows per block
#define TWB  128          // cols per block
#define PX   8            // pixels per thread
#define NTX  16           // TWB / PX
#define NT   128          // NTX * TH
#define PITCH 140         // 136 needed + 4 pad; 140 % 32 = 12 -> bank spread
#define NQ   35           // float4 per staged row
#define F4C  (KC * TH * NQ)   // 1120 float4 per chunk

// Map displacement (di,dj) -> output index in the reference's enumeration order.
__device__ __host__ constexpr int ord_idx(int di, int dj) {
  int i = di < 0 ? -di : di;
  int j = dj < 0 ? -dj : dj;
  if (i == 0 && j == 0) return 0;
  if (j == 0) return 1 + (i - 1) * 20 + (di > 0 ? 0 : 1);
  if (i == 0) return 1 + (j - 1) * 20 + (dj > 0 ? 2 : 3);
  return 1 + (i - 1) * 20 + 4 + (j - 1) * 4 +
         (di > 0 ? (dj > 0 ? 0 : 2) : (dj > 0 ? 1 : 3));
}

__global__ __launch_bounds__(NT, 3)   // cap VGPR ~168
void costvol_kernel(const float* __restrict__ src,
                    const float* __restrict__ tgt,
                    float* __restrict__ out) {
  __shared__ __align__(16) float lds[KC][TH][PITCH];

  const int tx  = threadIdx.x;           // 0..15
  const int ty  = threadIdx.y;           // 0..7
  const int tid = ty * NTX + tx;         // 0..127
  const int bx  = blockIdx.x;            // 0..1
  const int by  = blockIdx.y;            // 0..15
  const int bz  = blockIdx.z;            // 0..71 : b*9 + (di+4)
  const int b   = bz / 9;
  const int di  = (bz - b * 9) - S;      // wave-uniform, fixed per block

  const int w0b = bx * TWB;
  const int h0  = by * TH;
  const int h   = h0 + ty;
  const int w0  = w0b + tx * PX;

  float acc[9][PX];
#pragma unroll
  for (int o = 0; o < 9; ++o)
#pragma unroll
    for (int k = 0; k < PX; ++k) acc[o][k] = 0.f;

  for (int c0 = 0; c0 < CC; c0 += KC) {
    __syncthreads();   // protect LDS against readers of previous chunk

    // ---- stage tgt chunk: rows shifted by -di, 136-col halo, zero-padded ----
    // KC*TH*NQ = 1120 float4 over 128 threads -> 9 bounded iterations.
#pragma unroll
    for (int k = 0; k < 9; ++k) {
      const int f = tid + k * NT;
      if (f < F4C) {
        const int c   = f / (TH * NQ);        // /280
        const int rem = f - c * (TH * NQ);
        const int r   = rem / NQ;             // /35
        const int q   = rem - r * NQ;
        const int gh  = h0 - di + r;          // tgt row for output row h0+r
        const int gw  = w0b - S + 4 * q;      // multiple of 4: no straddle
        float4 v = make_float4(0.f, 0.f, 0.f, 0.f);
        if ((unsigned)gh < (unsigned)HH && gw >= 0 && gw + 3 < WW) {
          v = *reinterpret_cast<const float4*>(
                tgt + (((size_t)b * CC + (c0 + c)) * HH + gh) * WW + gw);
        }
        *reinterpret_cast<float4*>(&lds[c][r][4 * q]) = v;
      }
    }

    __syncthreads();

    // ---- compute: each thread reads ONLY its own row (r = ty) ----
#pragma unroll 2
    for (int c = 0; c < KC; ++c) {
      const float* sp = src + (((size_t)b * CC + (c0 + c)) * HH + h) * WW + w0;
      const float4 s0 = *reinterpret_cast<const float4*>(sp);
      const float4 s1 = *reinterpret_cast<const float4*>(sp + 4);
      const float sv[PX] = {s0.x, s0.y, s0.z, s0.w, s1.x, s1.y, s1.z, s1.w};

      // 16-float window: 4 aligned ds_read_b128
      const float4* rp = reinterpret_cast<const float4*>(&lds[c][ty][tx * PX]);
      float win[16];
#pragma unroll
      for (int q = 0; q < 4; ++q) {
        const float4 t = rp[q];
        win[4 * q]     = t.x;
        win[4 * q + 1] = t.y;
        win[4 * q + 2] = t.z;
        win[4 * q + 3] = t.w;
      }

#pragma unroll
      for (int dj = -S; dj <= S; ++dj) {
        const int o = dj + S;               // compile-time accumulator slot
#pragma unroll
        for (int k = 0; k < PX; ++k)
          acc[o][k] += sv[k] * win[k + S - dj];
      }
    }
  }

  // ---- store: 9 dj x 2 coalesced float4 stores ----
  const size_t HW = (size_t)HH * WW;
  float* op = out + (size_t)b * 81 * HW + (size_t)h * WW + w0;
#pragma unroll
  for (int dj = -S; dj <= S; ++dj) {
    const int o    = ord_idx(di, dj);       // uniform scalar epilogue
    const int slot = dj + S;
    *reinterpret_cast<float4*>(op + (size_t)o * HW) =
        make_float4(acc[slot][0], acc[slot][1], acc[slot][2], acc[slot][3]);
    *reinterpret_cast<float4*>(op + (size_t)o * HW + 4) =
        make_float4(acc[slot][4], acc[slot][5], acc[slot][6], acc[slot][7]);
  }
}

extern "C" void kernel_launch(void* const* d_in, const int* in_sizes, int n_in,
                              void* d_out, int out_size, void* d_ws, size_t ws_size,
                              hipStream_t stream) {
  const float* src = (const float*)d_in[0];
  const float* tgt = (const float*)d_in[1];
  float* out = (float*)d_out;
  // search_range (d_in[2]) is fixed at 4 per setup_inputs; geometry hardcoded.
  dim3 grid(WW / TWB, HH / TH, BB * 9);   // (2, 16, 72) = 2304 blocks
  dim3 block(NTX, TH, 1);                 // 128 threads
  costvol_kernel<<<grid, block, 0, stream>>>(src, tgt, out);
}